// Round 2
// baseline (70.526 us; speedup 1.0000x reference)
//
#include <hip/hip_runtime.h>
#include <math.h>

static constexpr int N   = 4096;  // IN_SIZE
static constexpr int H   = 5;     // HID
static constexpr int NO  = 2048;  // OUT_SIZE
static constexpr float FEPS = 1e-4f;
static constexpr int RPB = 8;     // X rows per block in k_xw1

// ws layout (floats):
// [0      , N*H)        : T  [4096][5]
// [N*H    , N*H + H*NO) : B  [5][2048]

__device__ __forceinline__ float wave_reduce(float v) {
#pragma unroll
    for (int o = 32; o > 0; o >>= 1) v += __shfl_down(v, o, 64);
    return v;
}

// T[i][a] = sum_j X[i][j] * W1[j][a]; 8 rows per block, W1 read directly
// (rows 4*j4..4*j4+3 of W1 are 20 contiguous floats = 5 float4 loads),
// reused across the 8 rows -> L2 traffic for W1 is 40 MB aggregate.
__global__ __launch_bounds__(256) void k_xw1(const float* __restrict__ X,
                                             const float* __restrict__ W1,
                                             float* __restrict__ T) {
    const int rb = blockIdx.x * RPB;
    const int t  = threadIdx.x;
    const float4* W14 = reinterpret_cast<const float4*>(W1);

    float acc[RPB][H];
#pragma unroll
    for (int r = 0; r < RPB; ++r)
#pragma unroll
        for (int a = 0; a < H; ++a) acc[r][a] = 0.f;

#pragma unroll
    for (int c = 0; c < 4; ++c) {
        const int j4 = c * 256 + t;   // float4 index within a row; W1 rows 4j4..4j4+3
        float wf[20];
        {
            const float4 f0 = W14[5 * j4 + 0];
            const float4 f1 = W14[5 * j4 + 1];
            const float4 f2 = W14[5 * j4 + 2];
            const float4 f3 = W14[5 * j4 + 3];
            const float4 f4 = W14[5 * j4 + 4];
            wf[0]=f0.x;  wf[1]=f0.y;  wf[2]=f0.z;  wf[3]=f0.w;
            wf[4]=f1.x;  wf[5]=f1.y;  wf[6]=f1.z;  wf[7]=f1.w;
            wf[8]=f2.x;  wf[9]=f2.y;  wf[10]=f2.z; wf[11]=f2.w;
            wf[12]=f3.x; wf[13]=f3.y; wf[14]=f3.z; wf[15]=f3.w;
            wf[16]=f4.x; wf[17]=f4.y; wf[18]=f4.z; wf[19]=f4.w;
        }
#pragma unroll
        for (int r = 0; r < RPB; ++r) {
            const float4 x = reinterpret_cast<const float4*>(
                                 X + (size_t)(rb + r) * N)[j4];
#pragma unroll
            for (int a = 0; a < H; ++a)
                acc[r][a] += x.x * wf[a]      + x.y * wf[5 + a]
                           + x.z * wf[10 + a] + x.w * wf[15 + a];
        }
    }

    // wave shfl reduce, then cross-wave via LDS (fixed-order, deterministic)
    __shared__ float sm[4][RPB * H];
    const int lane = t & 63, wv = t >> 6;
#pragma unroll
    for (int r = 0; r < RPB; ++r)
#pragma unroll
        for (int a = 0; a < H; ++a) {
            const float v = wave_reduce(acc[r][a]);
            if (lane == 0) sm[wv][r * H + a] = v;
        }
    __syncthreads();
    if (t < RPB * H)
        T[rb * H + t] = sm[0][t] + sm[1][t] + sm[2][t] + sm[3][t];
}

// One block: M = W1^T T (5x5) -> Jacobi eig of M M^T (double, thread 0,
// relative early-exit) -> y = U max(sqrt(lam),eps) U^T
// -> B = (y - eps*I) @ W2  (5 x 2048)
__global__ __launch_bounds__(256) void k_small(const float* __restrict__ W1,
                                               const float* __restrict__ W2,
                                               const float* __restrict__ T,
                                               float* __restrict__ B) {
    __shared__ float sm[4][H * H];
    __shared__ float Msum[H * H];
    __shared__ float ys[H * H];
    const int t = threadIdx.x;
    const int lane = t & 63, wv = t >> 6;

    float acc[H][H];
#pragma unroll
    for (int a = 0; a < H; ++a)
#pragma unroll
        for (int b = 0; b < H; ++b) acc[a][b] = 0.f;

    for (int i = t; i < N; i += 256) {
        float w[H], tv[H];
#pragma unroll
        for (int a = 0; a < H; ++a) w[a] = W1[i * H + a];
#pragma unroll
        for (int b = 0; b < H; ++b) tv[b] = T[i * H + b];
#pragma unroll
        for (int a = 0; a < H; ++a)
#pragma unroll
            for (int b = 0; b < H; ++b) acc[a][b] += w[a] * tv[b];
    }
#pragma unroll
    for (int a = 0; a < H; ++a)
#pragma unroll
        for (int b = 0; b < H; ++b) {
            const float v = wave_reduce(acc[a][b]);
            if (lane == 0) sm[wv][a * H + b] = v;
        }
    __syncthreads();
    if (t < H * H)
        Msum[t] = sm[0][t] + sm[1][t] + sm[2][t] + sm[3][t];
    __syncthreads();

    if (t == 0) {
        double Md[H][H], A[H][H], U[H][H];
        for (int a = 0; a < H; ++a)
            for (int b = 0; b < H; ++b) Md[a][b] = (double)Msum[a * H + b];
        // A = M M^T (symmetric PSD; eigvecs = left singular vecs of M)
        for (int a = 0; a < H; ++a)
            for (int b = 0; b < H; ++b) {
                double s = 0.0;
                for (int k = 0; k < H; ++k) s += Md[a][k] * Md[b][k];
                A[a][b] = s;
            }
        for (int a = 0; a < H; ++a)
            for (int b = 0; b < H; ++b) U[a][b] = (a == b) ? 1.0 : 0.0;
        // cyclic Jacobi, RELATIVE early exit (quadratic convergence: ~5 sweeps)
        for (int sweep = 0; sweep < 12; ++sweep) {
            double off = 0.0, sc = 0.0;
            for (int p = 0; p < H; ++p)
                for (int q = 0; q < H; ++q) {
                    sc += A[p][q] * A[p][q];
                    if (p < q) off += A[p][q] * A[p][q];
                }
            if (off <= 1e-15 * sc) break;
            const double skip = 1e-30 * sc;
            for (int p = 0; p < H - 1; ++p)
                for (int q = p + 1; q < H; ++q) {
                    double apq = A[p][q];
                    if (apq * apq <= skip) continue;
                    double theta = (A[q][q] - A[p][p]) / (2.0 * apq);
                    double tt = ((theta >= 0.0) ? 1.0 : -1.0) /
                                (fabs(theta) + sqrt(theta * theta + 1.0));
                    double c = 1.0 / sqrt(tt * tt + 1.0);
                    double s = tt * c;
                    for (int k = 0; k < H; ++k) {   // rows p,q: R^T A
                        double apk = A[p][k], aqk = A[q][k];
                        A[p][k] = c * apk - s * aqk;
                        A[q][k] = s * apk + c * aqk;
                    }
                    for (int k = 0; k < H; ++k) {   // cols p,q: (.) R
                        double akp = A[k][p], akq = A[k][q];
                        A[k][p] = c * akp - s * akq;
                        A[k][q] = s * akp + c * akq;
                    }
                    for (int k = 0; k < H; ++k) {   // U <- U R
                        double ukp = U[k][p], ukq = U[k][q];
                        U[k][p] = c * ukp - s * ukq;
                        U[k][q] = s * ukp + c * ukq;
                    }
                }
        }
        double e[H];
        for (int k = 0; k < H; ++k) {
            double lam = A[k][k];
            if (lam < 0.0) lam = 0.0;
            double sv = sqrt(lam);
            e[k] = (sv > (double)FEPS) ? sv : (double)FEPS;
        }
        for (int a = 0; a < H; ++a)
            for (int b = 0; b < H; ++b) {
                double s = 0.0;
                for (int k = 0; k < H; ++k) s += U[a][k] * e[k] * U[b][k];
                ys[a * H + b] = (float)s;
            }
    }
    __syncthreads();

    // B[k][j] = sum_m (y[k][m] - eps*delta) * W2[m][j]
    for (int p = t; p < H * NO; p += 256) {
        const int k = p / NO;
        const int j = p - k * NO;
        float s = 0.f;
#pragma unroll
        for (int m = 0; m < H; ++m) {
            float ym = ys[k * H + m] - ((k == m) ? FEPS : 0.f);
            s += ym * W2[m * NO + j];
        }
        B[p] = s;
    }
}

// z[i][j] = sum_k W2[k][i] * B[k][j] + eps*delta_ij ; float4 per thread.
__global__ __launch_bounds__(256) void k_out(const float* __restrict__ W2,
                                             const float* __restrict__ B,
                                             float* __restrict__ Z) {
    const int gid = blockIdx.x * 256 + threadIdx.x;   // [0, 2048*512)
    const int i  = gid >> 9;          // row
    const int jj = (gid & 511) << 2;  // col (float4)
    float w[H];
#pragma unroll
    for (int k = 0; k < H; ++k) w[k] = W2[k * NO + i];
    float av[4] = {0.f, 0.f, 0.f, 0.f};
#pragma unroll
    for (int k = 0; k < H; ++k) {
        const float4 b = *reinterpret_cast<const float4*>(B + k * NO + jj);
        av[0] += w[k] * b.x;
        av[1] += w[k] * b.y;
        av[2] += w[k] * b.z;
        av[3] += w[k] * b.w;
    }
    if (i >= jj && i < jj + 4) av[i - jj] += FEPS;
    float4 o = make_float4(av[0], av[1], av[2], av[3]);
    *reinterpret_cast<float4*>(Z + (size_t)i * NO + jj) = o;
}

extern "C" void kernel_launch(void* const* d_in, const int* in_sizes, int n_in,
                              void* d_out, int out_size, void* d_ws, size_t ws_size,
                              hipStream_t stream) {
    const float* X  = (const float*)d_in[0];
    const float* W1 = (const float*)d_in[1];
    const float* W2 = (const float*)d_in[2];
    float* out = (float*)d_out;
    float* ws  = (float*)d_ws;

    float* T = ws;            // 4096*5
    float* B = ws + N * H;    // 5*2048

    hipLaunchKernelGGL(k_xw1,   dim3(N / RPB), dim3(256), 0, stream, X, W1, T);
    hipLaunchKernelGGL(k_small, dim3(1),       dim3(256), 0, stream, W1, W2, T, B);
    hipLaunchKernelGGL(k_out,   dim3(NO * (NO / 4) / 256), dim3(256), 0, stream, W2, B, out);
}